// Round 1
// 501.833 us; speedup vs baseline: 1.0716x; 1.0716x over previous
//
#include <hip/hip_runtime.h>
#include <stdint.h>

// GraphAttentionLayer kernel set for MI355X (gfx950). Round 4.
// Pipeline (3 kernels — w is never materialized):
//   K1 conv_wt    : W[k][c] fp32 -> WT[c][k] bf16 (LDS-tiled transpose)
//   K2 wh_gemm    : Wh = h@W + bW via bf16 MFMA -> WhT[c][i] bf16
//                   + fused epilogue: raw scores s1 = Wh@a1, s2 = Wh@a2
//   K3 fused_attn : out = softmax_row(mask(lrelu(s1_i+s2_j))) @ Wh.
//                   The attention matrix w is computed ON THE FLY in the
//                   A-staging path of the PV GEMM (adj int4 loads -> exp ->
//                   swizzled ds_write), row-sums accumulated in registers
//                   across the full K loop, dinv applied in the epilogue.
//                   Saves the 128 MB w HBM round trip + the whole w_k kernel.
//   Tile 64x128, BK=128, 512 thr, XOR-16 LDS swizzle, XCD-aware block map
//   (4 blocks sharing a row-stripe are 128 apart == same XCD -> adj row
//   fetched from HBM once, 3x from L2).

#define NN 8192
#define DD 512

typedef __attribute__((ext_vector_type(8))) short short8;
typedef __attribute__((ext_vector_type(8))) unsigned short ushort8;
typedef __attribute__((ext_vector_type(4))) float f32x4;
typedef __attribute__((ext_vector_type(4))) float float4v;
typedef __attribute__((ext_vector_type(4))) unsigned short ushort4v;

__device__ __forceinline__ uint16_t f2bf(float f) {
  union { float f; uint32_t u; } v; v.f = f;
  uint32_t u = v.u;
  u += 0x7fffu + ((u >> 16) & 1u);   // round-nearest-even
  return (uint16_t)(u >> 16);
}
__device__ __forceinline__ float bf2f(uint16_t b) {
  union { uint32_t u; float f; } v; v.u = ((uint32_t)b) << 16;
  return v.f;
}

__device__ __forceinline__ void async_copy16(uint16_t* lds, const uint16_t* g) {
  __builtin_amdgcn_global_load_lds(
      (const __attribute__((address_space(1))) uint32_t*)g,
      (__attribute__((address_space(3))) uint32_t*)lds, 16, 0, 0);
}

// ---- K1: tiled transpose+convert W (512x512) ----
__global__ __launch_bounds__(256) void conv_wt(const float* __restrict__ W,
                                               uint16_t* __restrict__ WT) {
  __shared__ float ts[64][65];
  int tid = threadIdx.x;
  int kt = (blockIdx.x >> 3) * 64, ct = (blockIdx.x & 7) * 64;
  #pragma unroll
  for (int it = 0; it < 4; ++it) {
    int idx = it * 256 + tid;
    int r = idx >> 4, q = idx & 15;
    float4v v = *(const float4v*)(W + (size_t)(kt + r) * 512 + ct + q * 4);
    ts[r][q * 4 + 0] = v.x; ts[r][q * 4 + 1] = v.y;
    ts[r][q * 4 + 2] = v.z; ts[r][q * 4 + 3] = v.w;
  }
  __syncthreads();
  #pragma unroll
  for (int it = 0; it < 4; ++it) {
    int idx = it * 256 + tid;
    int c = idx >> 4, q = idx & 15;
    ushort4v p;
    p.x = f2bf(ts[q * 4 + 0][c]); p.y = f2bf(ts[q * 4 + 1][c]);
    p.z = f2bf(ts[q * 4 + 2][c]); p.w = f2bf(ts[q * 4 + 3][c]);
    *(ushort4v*)(WT + (size_t)(ct + c) * 512 + kt + q * 4) = p;
  }
}

// ---- K2: Wh GEMM -> WhT[c][i] bf16, fused raw scores s1,s2 ----
__global__ __launch_bounds__(512) void wh_gemm(const float* __restrict__ h,
                                               const uint16_t* __restrict__ WT,
                                               const float* __restrict__ bW,
                                               const float* __restrict__ a1,
                                               const float* __restrict__ a2,
                                               uint16_t* __restrict__ WhT,
                                               float* __restrict__ s1g,
                                               float* __restrict__ s2g) {
  __shared__ __align__(16) uint16_t At[32 * 32];
  __shared__ __align__(16) uint16_t Bt[512 * 32];
  __shared__ float s1loc[32], s2loc[32];
  int tid = threadIdx.x;
  int wave = tid >> 6, lane = tid & 63;
  int l15 = lane & 15, quad = lane >> 4;
  int i0 = blockIdx.x * 32;
  if (tid < 32) { s1loc[tid] = 0.f; s2loc[tid] = 0.f; }
  f32x4 acc[2][4] = {};
  for (int k0 = 0; k0 < 512; k0 += 32) {
    if (tid < 256) {
      int r = tid >> 3, ks = (tid & 7) * 4;
      float4v hv = *(const float4v*)(h + (size_t)(i0 + r) * 512 + k0 + ks);
      ushort4v p;
      p.x = f2bf(hv.x); p.y = f2bf(hv.y); p.z = f2bf(hv.z); p.w = f2bf(hv.w);
      *(ushort4v*)&At[r * 32 + ks] = p;
    }
    #pragma unroll
    for (int rr = 0; rr < 4; ++rr) {
      int idx = rr * 512 + tid;
      int c = idx >> 2, q = idx & 3;
      async_copy16(&Bt[idx * 8], WT + c * 512 + k0 + q * 8);
    }
    __syncthreads();
    short8 a0 = *(const short8*)&At[l15 * 32 + quad * 8];
    short8 a1f = *(const short8*)&At[(l15 + 16) * 32 + quad * 8];
    #pragma unroll
    for (int nt = 0; nt < 4; ++nt) {
      int c = wave * 64 + nt * 16 + l15;
      short8 b = *(const short8*)&Bt[c * 32 + quad * 8];
      acc[0][nt] = __builtin_amdgcn_mfma_f32_16x16x32_bf16(a0, b, acc[0][nt], 0, 0, 0);
      acc[1][nt] = __builtin_amdgcn_mfma_f32_16x16x32_bf16(a1f, b, acc[1][nt], 0, 0, 0);
    }
    __syncthreads();
  }
  // epilogue: bias, write WhT, per-row score partials
  #pragma unroll
  for (int mt = 0; mt < 2; ++mt) {
    int ib = i0 + mt * 16 + quad * 4;
    float r1[4] = {0.f, 0.f, 0.f, 0.f};
    float r2[4] = {0.f, 0.f, 0.f, 0.f};
    #pragma unroll
    for (int nt = 0; nt < 4; ++nt) {
      int c = wave * 64 + nt * 16 + l15;
      float bias = bW[c];
      float a1c = a1[c], a2c = a2[c];
      float v0 = acc[mt][nt].x + bias;
      float v1 = acc[mt][nt].y + bias;
      float v2 = acc[mt][nt].z + bias;
      float v3 = acc[mt][nt].w + bias;
      ushort4v p;
      p.x = f2bf(v0); p.y = f2bf(v1); p.z = f2bf(v2); p.w = f2bf(v3);
      *(ushort4v*)&WhT[(size_t)c * 8192 + ib] = p;
      r1[0] = fmaf(v0, a1c, r1[0]); r1[1] = fmaf(v1, a1c, r1[1]);
      r1[2] = fmaf(v2, a1c, r1[2]); r1[3] = fmaf(v3, a1c, r1[3]);
      r2[0] = fmaf(v0, a2c, r2[0]); r2[1] = fmaf(v1, a2c, r2[1]);
      r2[2] = fmaf(v2, a2c, r2[2]); r2[3] = fmaf(v3, a2c, r2[3]);
    }
    #pragma unroll
    for (int v = 0; v < 4; ++v) {
      int row = mt * 16 + quad * 4 + v;
      atomicAdd(&s1loc[row], r1[v]);
      atomicAdd(&s2loc[row], r2[v]);
    }
  }
  __syncthreads();
  if (tid < 32) {
    s1g[i0 + tid] = s1loc[tid];
    s2g[i0 + tid] = s2loc[tid];
  }
}

// per-element score: e = lrelu(base + s2j); w = adj>0 ? exp(e) : 0 (bf16)
#define WCOMP(dstv, slot, aval, sval, basev, rs)                    \
  { float e_ = (basev) + (sval); e_ = fmaxf(e_, 0.2f * e_);         \
    float wv_ = ((aval) > 0) ? __expf(e_) : 0.f;                    \
    uint16_t u_ = f2bf(wv_); (dstv)[slot] = u_; (rs) += bf2f(u_); }

// ---- K3: fused attention: out = (w @ WhT^T) * dinv, w computed on the fly.
// 64x128 tile, BK=128, 512 thr. Block map: rb = blockIdx&127, cb =
// blockIdx>>7 -> the 4 blocks sharing an adj row-stripe are 128 apart ==
// same XCD (round-robin %8) -> adj fetched from HBM once, L2 for the rest.
// Each thread owns rows (tid>>4, tid>>4+32), chunk sc = p^(r&15) of every
// K-step -> accumulates its slice of the softmax row-sum across the full
// j loop; 16-lane shfl reduce gives dinv in-block (no global pass).
__global__ __launch_bounds__(512, 4) void fused_attn(const int* __restrict__ adj,
                                                     const float* __restrict__ s1,
                                                     const float* __restrict__ s2,
                                                     const float* __restrict__ b1,
                                                     const float* __restrict__ b2,
                                                     const uint16_t* __restrict__ WhT,
                                                     float* __restrict__ out) {
  __shared__ __align__(16) uint16_t At[64 * 128];    // 16 KB, XOR-16 swizzled
  __shared__ __align__(16) uint16_t Bt[128 * 128];   // 32 KB, XOR-16 swizzled
  __shared__ float sdv[64];
  int tid = threadIdx.x;
  int wave = tid >> 6, lane = tid & 63;
  int l15 = lane & 15, quad = lane >> 4;
  int rb = blockIdx.x & 127, cb = blockIdx.x >> 7;
  int i0 = rb * 64, c0 = cb * 128;
  int r0 = tid >> 4, pp = tid & 15;           // r0 in [0,32), chunk slot pp
  int sc = pp ^ (r0 & 15);                    // source chunk (involution)
  const int* arow0 = adj + (size_t)(i0 + r0) * NN + sc * 8;
  const int* arow1 = arow0 + (size_t)32 * NN;
  float bias = b1[0] + b2[0];
  float base0 = s1[i0 + r0] + bias;
  float base1 = s1[i0 + r0 + 32] + bias;
  float rsum0 = 0.f, rsum1 = 0.f;
  uint16_t* at0 = &At[(r0 * 16 + pp) * 8];
  uint16_t* at1 = &At[((r0 + 32) * 16 + pp) * 8];
  f32x4 acc[4] = {};
  for (int j0 = 0; j0 < NN; j0 += 128) {
    // A inputs first (oldest in vmcnt queue -> compute can start at vmcnt(4)
    // while the 4 B-copies below are still in flight)
    int4 a00 = *(const int4*)(arow0 + j0);
    int4 a01 = *(const int4*)(arow0 + j0 + 4);
    int4 a10 = *(const int4*)(arow1 + j0);
    int4 a11 = *(const int4*)(arow1 + j0 + 4);
    float4v sv0 = *(const float4v*)(s2 + j0 + sc * 8);
    float4v sv1 = *(const float4v*)(s2 + j0 + sc * 8 + 4);
    // B: 128 rows x 128 j = 32 KB = 2048 x 16B chunks, 4/thread (async DMA).
    // LDS dst linear in tid (global_load_lds constraint); source chunk
    // XOR-swizzled so LDS pos q of row r holds global chunk q^(r&15).
    #pragma unroll
    for (int it = 0; it < 4; ++it) {
      int idx = it * 512 + tid;
      int r = idx >> 4, q = idx & 15;
      int bsc = q ^ (r & 15);
      async_copy16(&Bt[idx * 8], WhT + (size_t)(c0 + r) * NN + j0 + bsc * 8);
    }
    // compute 8 w values per row, pack bf16x8, swizzled ds_write
    ushort8 w0, w1;
    WCOMP(w0, 0, a00.x, sv0.x, base0, rsum0);
    WCOMP(w0, 1, a00.y, sv0.y, base0, rsum0);
    WCOMP(w0, 2, a00.z, sv0.z, base0, rsum0);
    WCOMP(w0, 3, a00.w, sv0.w, base0, rsum0);
    WCOMP(w0, 4, a01.x, sv1.x, base0, rsum0);
    WCOMP(w0, 5, a01.y, sv1.y, base0, rsum0);
    WCOMP(w0, 6, a01.z, sv1.z, base0, rsum0);
    WCOMP(w0, 7, a01.w, sv1.w, base0, rsum0);
    WCOMP(w1, 0, a10.x, sv0.x, base1, rsum1);
    WCOMP(w1, 1, a10.y, sv0.y, base1, rsum1);
    WCOMP(w1, 2, a10.z, sv0.z, base1, rsum1);
    WCOMP(w1, 3, a10.w, sv0.w, base1, rsum1);
    WCOMP(w1, 4, a11.x, sv1.x, base1, rsum1);
    WCOMP(w1, 5, a11.y, sv1.y, base1, rsum1);
    WCOMP(w1, 6, a11.z, sv1.z, base1, rsum1);
    WCOMP(w1, 7, a11.w, sv1.w, base1, rsum1);
    *(ushort8*)at0 = w0;
    *(ushort8*)at1 = w1;
    __syncthreads();
    int brow = wave * 16 + l15;
    #pragma unroll
    for (int ks = 0; ks < 4; ++ks) {
      int ch = ks * 4 + quad;
      short8 b = *(const short8*)&Bt[brow * 128 + ((ch ^ (brow & 15)) * 8)];
      #pragma unroll
      for (int rt = 0; rt < 4; ++rt) {
        int ar = rt * 16 + l15;
        short8 a = *(const short8*)&At[ar * 128 + ((ch ^ (ar & 15)) * 8)];
        acc[rt] = __builtin_amdgcn_mfma_f32_16x16x32_bf16(a, b, acc[rt], 0, 0, 0);
      }
    }
    __syncthreads();
  }
  // dinv: reduce the 16 chunk-partials of each row (16 consecutive lanes)
  #pragma unroll
  for (int o = 1; o < 16; o <<= 1) {
    rsum0 += __shfl_xor(rsum0, o);
    rsum1 += __shfl_xor(rsum1, o);
  }
  if (pp == 0) {
    sdv[r0] = 1.0f / rsum0;
    sdv[r0 + 32] = 1.0f / rsum1;
  }
  __syncthreads();
  #pragma unroll
  for (int rt = 0; rt < 4; ++rt) {
    #pragma unroll
    for (int v = 0; v < 4; ++v) {
      int rloc = rt * 16 + quad * 4 + v;
      out[(size_t)(i0 + rloc) * DD + c0 + wave * 16 + l15] = acc[rt][v] * sdv[rloc];
    }
  }
}

extern "C" void kernel_launch(void* const* d_in, const int* in_sizes, int n_in,
                              void* d_out, int out_size, void* d_ws, size_t ws_size,
                              hipStream_t stream) {
  const float* h   = (const float*)d_in[0];
  const int*   adj = (const int*)d_in[1];
  const float* W   = (const float*)d_in[2];
  const float* bW  = (const float*)d_in[3];
  const float* a1  = (const float*)d_in[4];
  const float* b1  = (const float*)d_in[5];
  const float* a2  = (const float*)d_in[6];
  const float* b2  = (const float*)d_in[7];
  float* out = (float*)d_out;
  char* ws = (char*)d_ws;

  uint16_t* WhT = (uint16_t*)(ws);                 // 8388608
  uint16_t* WT  = (uint16_t*)(ws + 8388608);       // 524288
  float* s1     = (float*)(ws + 8912896);          // 32768
  float* s2     = (float*)(ws + 8945664);          // 32768

  conv_wt<<<64, 256, 0, stream>>>(W, WT);
  wh_gemm<<<256, 512, 0, stream>>>(h, WT, bW, a1, a2, WhT, s1, s2);
  fused_attn<<<512, 512, 0, stream>>>(adj, s1, s2, b1, b2, WhT, out);
}

// Round 2
// 500.466 us; speedup vs baseline: 1.0746x; 1.0027x over previous
//
#include <hip/hip_runtime.h>
#include <hip/hip_bf16.h>
#include <stdint.h>

// GraphAttentionLayer kernel set for MI355X (gfx950). Round 5.
// Pipeline (3 kernels — w never materialized):
//   K1 conv_wt    : W[k][c] fp32 -> WT[c][k] bf16 (LDS-tiled transpose)
//   K2 wh_gemm    : Wh = h@W + bW via bf16 MFMA -> WhT[c][i] bf16
//                   + fused raw scores s1 = Wh@a1 (+epilogue exp factors
//                   eb1 = exp(s2_j), eb2 = exp(0.2*s2_j))
//   K3 fused_attn : out = softmax_row(mask(lrelu(s1_i+s2_j))) @ Wh.
//     Round-5 changes vs round-4:
//      * score math factored: exp(lrelu(t)) == max(exp(t), exp(0.2t)) and
//        exp(t) = exp(base_i)*eb1[j] -> inner loop is 2 mul + max + cndmask,
//        NO transcendental, bf16 pack via native v_cvt_pk_bf16_f32.
//      * split-K wave mapping (2 rg x 2 cg x 2 kg): each wave owns a
//        32x64 output tile over half the K-chunk -> A-tile LDS reads drop
//        from 8x-redundant (160 KB/blk-iter) to 96 KB/blk-iter. One
//        cross-wave acc reduction through LDS at the end.
//   Tile 64x128, BK=128, 512 thr, XOR-16 LDS swizzle, XCD-aware block map.

#define NN 8192
#define DD 512

typedef __attribute__((ext_vector_type(8))) short short8;
typedef __attribute__((ext_vector_type(8))) unsigned short ushort8;
typedef __attribute__((ext_vector_type(4))) float f32x4;
typedef __attribute__((ext_vector_type(4))) float float4v;
typedef __attribute__((ext_vector_type(4))) unsigned short ushort4v;

__device__ __forceinline__ uint16_t f2bf(float f) {
  union { float f; uint32_t u; } v; v.f = f;
  uint32_t u = v.u;
  u += 0x7fffu + ((u >> 16) & 1u);   // round-nearest-even
  return (uint16_t)(u >> 16);
}

// packed f32 pair -> bf16x2 (RNE) via native v_cvt_pk_bf16_f32
__device__ __forceinline__ uint32_t pk2bf(float lo, float hi) {
  union { __hip_bfloat162 h; uint32_t u; } v;
  v.h = __float22bfloat162_rn(make_float2(lo, hi));
  return v.u;
}

__device__ __forceinline__ void async_copy16(uint16_t* lds, const uint16_t* g) {
  __builtin_amdgcn_global_load_lds(
      (const __attribute__((address_space(1))) uint32_t*)g,
      (__attribute__((address_space(3))) uint32_t*)lds, 16, 0, 0);
}

// ---- K1: tiled transpose+convert W (512x512) ----
__global__ __launch_bounds__(256) void conv_wt(const float* __restrict__ W,
                                               uint16_t* __restrict__ WT) {
  __shared__ float ts[64][65];
  int tid = threadIdx.x;
  int kt = (blockIdx.x >> 3) * 64, ct = (blockIdx.x & 7) * 64;
  #pragma unroll
  for (int it = 0; it < 4; ++it) {
    int idx = it * 256 + tid;
    int r = idx >> 4, q = idx & 15;
    float4v v = *(const float4v*)(W + (size_t)(kt + r) * 512 + ct + q * 4);
    ts[r][q * 4 + 0] = v.x; ts[r][q * 4 + 1] = v.y;
    ts[r][q * 4 + 2] = v.z; ts[r][q * 4 + 3] = v.w;
  }
  __syncthreads();
  #pragma unroll
  for (int it = 0; it < 4; ++it) {
    int idx = it * 256 + tid;
    int c = idx >> 4, q = idx & 15;
    ushort4v p;
    p.x = f2bf(ts[q * 4 + 0][c]); p.y = f2bf(ts[q * 4 + 1][c]);
    p.z = f2bf(ts[q * 4 + 2][c]); p.w = f2bf(ts[q * 4 + 3][c]);
    *(ushort4v*)(WT + (size_t)(ct + c) * 512 + kt + q * 4) = p;
  }
}

// ---- K2: Wh GEMM -> WhT[c][i] bf16, fused raw scores + exp factors ----
__global__ __launch_bounds__(512) void wh_gemm(const float* __restrict__ h,
                                               const uint16_t* __restrict__ WT,
                                               const float* __restrict__ bW,
                                               const float* __restrict__ a1,
                                               const float* __restrict__ a2,
                                               uint16_t* __restrict__ WhT,
                                               float* __restrict__ s1g,
                                               float* __restrict__ eb1g,
                                               float* __restrict__ eb2g) {
  __shared__ __align__(16) uint16_t At[32 * 32];
  __shared__ __align__(16) uint16_t Bt[512 * 32];
  __shared__ float s1loc[32], s2loc[32];
  int tid = threadIdx.x;
  int wave = tid >> 6, lane = tid & 63;
  int l15 = lane & 15, quad = lane >> 4;
  int i0 = blockIdx.x * 32;
  if (tid < 32) { s1loc[tid] = 0.f; s2loc[tid] = 0.f; }
  f32x4 acc[2][4] = {};
  for (int k0 = 0; k0 < 512; k0 += 32) {
    if (tid < 256) {
      int r = tid >> 3, ks = (tid & 7) * 4;
      float4v hv = *(const float4v*)(h + (size_t)(i0 + r) * 512 + k0 + ks);
      ushort4v p;
      p.x = f2bf(hv.x); p.y = f2bf(hv.y); p.z = f2bf(hv.z); p.w = f2bf(hv.w);
      *(ushort4v*)&At[r * 32 + ks] = p;
    }
    #pragma unroll
    for (int rr = 0; rr < 4; ++rr) {
      int idx = rr * 512 + tid;
      int c = idx >> 2, q = idx & 3;
      async_copy16(&Bt[idx * 8], WT + c * 512 + k0 + q * 8);
    }
    __syncthreads();
    short8 a0 = *(const short8*)&At[l15 * 32 + quad * 8];
    short8 a1f = *(const short8*)&At[(l15 + 16) * 32 + quad * 8];
    #pragma unroll
    for (int nt = 0; nt < 4; ++nt) {
      int c = wave * 64 + nt * 16 + l15;
      short8 b = *(const short8*)&Bt[c * 32 + quad * 8];
      acc[0][nt] = __builtin_amdgcn_mfma_f32_16x16x32_bf16(a0, b, acc[0][nt], 0, 0, 0);
      acc[1][nt] = __builtin_amdgcn_mfma_f32_16x16x32_bf16(a1f, b, acc[1][nt], 0, 0, 0);
    }
    __syncthreads();
  }
  // epilogue: bias, write WhT, per-row score partials
  #pragma unroll
  for (int mt = 0; mt < 2; ++mt) {
    int ib = i0 + mt * 16 + quad * 4;
    float r1[4] = {0.f, 0.f, 0.f, 0.f};
    float r2[4] = {0.f, 0.f, 0.f, 0.f};
    #pragma unroll
    for (int nt = 0; nt < 4; ++nt) {
      int c = wave * 64 + nt * 16 + l15;
      float bias = bW[c];
      float a1c = a1[c], a2c = a2[c];
      float v0 = acc[mt][nt].x + bias;
      float v1 = acc[mt][nt].y + bias;
      float v2 = acc[mt][nt].z + bias;
      float v3 = acc[mt][nt].w + bias;
      ushort4v p;
      p.x = f2bf(v0); p.y = f2bf(v1); p.z = f2bf(v2); p.w = f2bf(v3);
      *(ushort4v*)&WhT[(size_t)c * 8192 + ib] = p;
      r1[0] = fmaf(v0, a1c, r1[0]); r1[1] = fmaf(v1, a1c, r1[1]);
      r1[2] = fmaf(v2, a1c, r1[2]); r1[3] = fmaf(v3, a1c, r1[3]);
      r2[0] = fmaf(v0, a2c, r2[0]); r2[1] = fmaf(v1, a2c, r2[1]);
      r2[2] = fmaf(v2, a2c, r2[2]); r2[3] = fmaf(v3, a2c, r2[3]);
    }
    #pragma unroll
    for (int v = 0; v < 4; ++v) {
      int row = mt * 16 + quad * 4 + v;
      atomicAdd(&s1loc[row], r1[v]);
      atomicAdd(&s2loc[row], r2[v]);
    }
  }
  __syncthreads();
  if (tid < 32) {
    s1g[i0 + tid] = s1loc[tid];
    float v2 = s2loc[tid];
    eb1g[i0 + tid] = __expf(v2);
    eb2g[i0 + tid] = __expf(0.2f * v2);
  }
}

// score: w = adj>0 ? max(A1*eb1_j, A2*eb2_j) : 0   (== adj?exp(lrelu(t)):0)
#define SCORE(aval, e1, e2, A1v, A2v, rs, dst)                       \
  { float m_ = fmaxf((A1v) * (e1), (A2v) * (e2));                    \
    m_ = ((aval) > 0) ? m_ : 0.f;                                    \
    (rs) += m_; (dst) = m_; }

// ---- K3: fused attention: out = (w @ WhT^T) * dinv, w computed on the fly.
// 64x128 tile, BK=128, 512 thr = 8 waves as (rg 2 x cg 2 x kg 2):
//   wave -> kg = w&1 (K half), rg = (w>>1)&1 (32-row group), cg = w>>2
//   (64-col group). Per wave per iter: 4 A-reads + 8 B-reads + 16 MFMA.
// Block map: rb = blockIdx&127, cb = blockIdx>>7 -> 4 blocks sharing an adj
// row-stripe are 128 apart == same XCD -> adj HBM-fetched once.
__global__ __launch_bounds__(512, 4) void fused_attn(const int* __restrict__ adj,
                                                     const float* __restrict__ s1,
                                                     const float* __restrict__ b1,
                                                     const float* __restrict__ b2,
                                                     const float* __restrict__ eb1,
                                                     const float* __restrict__ eb2,
                                                     const uint16_t* __restrict__ WhT,
                                                     float* __restrict__ out) {
  __shared__ __align__(16) uint16_t At[64 * 128];    // 16 KB, XOR-16 swizzled
  __shared__ __align__(16) uint16_t Bt[128 * 128];   // 32 KB, XOR-16 swizzled
  __shared__ float sdv[64];
  int tid = threadIdx.x;
  int wave = tid >> 6, lane = tid & 63;
  int l15 = lane & 15, quad = lane >> 4;
  int kg = wave & 1, rg = (wave >> 1) & 1, cg = wave >> 2;
  int rb = blockIdx.x & 127, cb = blockIdx.x >> 7;
  int i0 = rb * 64, c0 = cb * 128;
  int r0 = tid >> 4, pp = tid & 15;           // r0 in [0,32), chunk slot pp
  int sc = pp ^ (r0 & 15);                    // source chunk (involution)
  const int* arow0 = adj + (size_t)(i0 + r0) * NN + sc * 8;
  const int* arow1 = arow0 + (size_t)32 * NN;
  float bias = b1[0] + b2[0];
  float base0 = s1[i0 + r0] + bias;
  float base1 = s1[i0 + r0 + 32] + bias;
  float A10 = __expf(base0), A20 = __expf(0.2f * base0);
  float A11 = __expf(base1), A21 = __expf(0.2f * base1);
  float rsum0 = 0.f, rsum1 = 0.f;
  uint16_t* at0 = &At[(r0 * 16 + pp) * 8];
  uint16_t* at1 = &At[((r0 + 32) * 16 + pp) * 8];
  f32x4 acc[2][4] = {};
  for (int j0 = 0; j0 < NN; j0 += 128) {
    // A inputs first (oldest in vmcnt queue)
    int4 a00 = *(const int4*)(arow0 + j0);
    int4 a01 = *(const int4*)(arow0 + j0 + 4);
    int4 a10 = *(const int4*)(arow1 + j0);
    int4 a11 = *(const int4*)(arow1 + j0 + 4);
    float4v e1v0 = *(const float4v*)(eb1 + j0 + sc * 8);
    float4v e1v1 = *(const float4v*)(eb1 + j0 + sc * 8 + 4);
    float4v e2v0 = *(const float4v*)(eb2 + j0 + sc * 8);
    float4v e2v1 = *(const float4v*)(eb2 + j0 + sc * 8 + 4);
    // B: 128 rows x 128 j = 32 KB = 2048 x 16B chunks, 4/thread (async DMA)
    #pragma unroll
    for (int it = 0; it < 4; ++it) {
      int idx = it * 512 + tid;
      int r = idx >> 4, q = idx & 15;
      int bsc = q ^ (r & 15);
      async_copy16(&Bt[idx * 8], WhT + (size_t)(c0 + r) * NN + j0 + bsc * 8);
    }
    // scores: no transcendentals in the loop (factored exp), pack via cvt_pk
    float t0[8], t1[8];
    SCORE(a00.x, e1v0.x, e2v0.x, A10, A20, rsum0, t0[0]);
    SCORE(a00.y, e1v0.y, e2v0.y, A10, A20, rsum0, t0[1]);
    SCORE(a00.z, e1v0.z, e2v0.z, A10, A20, rsum0, t0[2]);
    SCORE(a00.w, e1v0.w, e2v0.w, A10, A20, rsum0, t0[3]);
    SCORE(a01.x, e1v1.x, e2v1.x, A10, A20, rsum0, t0[4]);
    SCORE(a01.y, e1v1.y, e2v1.y, A10, A20, rsum0, t0[5]);
    SCORE(a01.z, e1v1.z, e2v1.z, A10, A20, rsum0, t0[6]);
    SCORE(a01.w, e1v1.w, e2v1.w, A10, A20, rsum0, t0[7]);
    SCORE(a10.x, e1v0.x, e2v0.x, A11, A21, rsum1, t1[0]);
    SCORE(a10.y, e1v0.y, e2v0.y, A11, A21, rsum1, t1[1]);
    SCORE(a10.z, e1v0.z, e2v0.z, A11, A21, rsum1, t1[2]);
    SCORE(a10.w, e1v0.w, e2v0.w, A11, A21, rsum1, t1[3]);
    SCORE(a11.x, e1v1.x, e2v1.x, A11, A21, rsum1, t1[4]);
    SCORE(a11.y, e1v1.y, e2v1.y, A11, A21, rsum1, t1[5]);
    SCORE(a11.z, e1v1.z, e2v1.z, A11, A21, rsum1, t1[6]);
    SCORE(a11.w, e1v1.w, e2v1.w, A11, A21, rsum1, t1[7]);
    ushort8 w0, w1;
    uint32_t* pw0 = (uint32_t*)&w0;
    uint32_t* pw1 = (uint32_t*)&w1;
    pw0[0] = pk2bf(t0[0], t0[1]); pw0[1] = pk2bf(t0[2], t0[3]);
    pw0[2] = pk2bf(t0[4], t0[5]); pw0[3] = pk2bf(t0[6], t0[7]);
    pw1[0] = pk2bf(t1[0], t1[1]); pw1[1] = pk2bf(t1[2], t1[3]);
    pw1[2] = pk2bf(t1[4], t1[5]); pw1[3] = pk2bf(t1[6], t1[7]);
    *(ushort8*)at0 = w0;
    *(ushort8*)at1 = w1;
    __syncthreads();
    // MFMA phase: split-K — wave covers k in [kg*64, kg*64+64)
    #pragma unroll
    for (int kc = 0; kc < 2; ++kc) {
      int ch = kg * 8 + kc * 4 + quad;
      int ar0 = rg * 32 + l15, ar1 = ar0 + 16;
      short8 a0 = *(const short8*)&At[ar0 * 128 + ((ch ^ (ar0 & 15)) * 8)];
      short8 a1f = *(const short8*)&At[ar1 * 128 + ((ch ^ (ar1 & 15)) * 8)];
      #pragma unroll
      for (int ct = 0; ct < 4; ++ct) {
        int br = cg * 64 + ct * 16 + l15;
        short8 b = *(const short8*)&Bt[br * 128 + ((ch ^ (br & 15)) * 8)];
        acc[0][ct] = __builtin_amdgcn_mfma_f32_16x16x32_bf16(a0, b, acc[0][ct], 0, 0, 0);
        acc[1][ct] = __builtin_amdgcn_mfma_f32_16x16x32_bf16(a1f, b, acc[1][ct], 0, 0, 0);
      }
    }
    __syncthreads();
  }
  // dinv: reduce the 16 chunk-partials of each row (16 consecutive lanes)
  #pragma unroll
  for (int o = 1; o < 16; o <<= 1) {
    rsum0 += __shfl_xor(rsum0, o);
    rsum1 += __shfl_xor(rsum1, o);
  }
  if (pp == 0) {
    sdv[r0] = 1.0f / rsum0;
    sdv[r0 + 32] = 1.0f / rsum1;
  }
  // split-K reduction: kg=1 waves dump acc into Bt, kg=0 add + scale + store
  float* red = (float*)Bt;
  int pid = rg * 2 + cg;
  if (kg == 1) {
    #pragma unroll
    for (int rt = 0; rt < 2; ++rt)
      #pragma unroll
      for (int ct = 0; ct < 4; ++ct)
        #pragma unroll
        for (int v = 0; v < 4; ++v)
          red[pid * 2048 + ((rt * 4 + ct) * 4 + v) * 64 + lane] = acc[rt][ct][v];
  }
  __syncthreads();
  if (kg == 0) {
    #pragma unroll
    for (int rt = 0; rt < 2; ++rt) {
      #pragma unroll
      for (int v = 0; v < 4; ++v) {
        int rloc = rg * 32 + rt * 16 + quad * 4 + v;
        float dv = sdv[rloc];
        #pragma unroll
        for (int ct = 0; ct < 4; ++ct) {
          float s = acc[rt][ct][v] + red[pid * 2048 + ((rt * 4 + ct) * 4 + v) * 64 + lane];
          out[(size_t)(i0 + rloc) * DD + c0 + cg * 64 + ct * 16 + l15] = s * dv;
        }
      }
    }
  }
}

extern "C" void kernel_launch(void* const* d_in, const int* in_sizes, int n_in,
                              void* d_out, int out_size, void* d_ws, size_t ws_size,
                              hipStream_t stream) {
  const float* h   = (const float*)d_in[0];
  const int*   adj = (const int*)d_in[1];
  const float* W   = (const float*)d_in[2];
  const float* bW  = (const float*)d_in[3];
  const float* a1  = (const float*)d_in[4];
  const float* b1  = (const float*)d_in[5];
  const float* a2  = (const float*)d_in[6];
  const float* b2  = (const float*)d_in[7];
  float* out = (float*)d_out;
  char* ws = (char*)d_ws;

  uint16_t* WhT = (uint16_t*)(ws);                 // 8388608
  uint16_t* WT  = (uint16_t*)(ws + 8388608);       // 524288
  float* s1     = (float*)(ws + 8912896);          // 32768
  float* eb1    = (float*)(ws + 8945664);          // 32768
  float* eb2    = (float*)(ws + 8978432);          // 32768

  conv_wt<<<64, 256, 0, stream>>>(W, WT);
  wh_gemm<<<256, 512, 0, stream>>>(h, WT, bW, a1, a2, WhT, s1, eb1, eb2);
  fused_attn<<<512, 512, 0, stream>>>(adj, s1, b1, b2, eb1, eb2, WhT, out);
}